// Round 1
// baseline (2164.298 us; speedup 1.0000x reference)
//
#include <hip/hip_runtime.h>
#include <hip/hip_bf16.h>

#define NEGV (-1e9f)

// ---------------------------------------------------------------------------
// JAX threefry2x32 (key = (0,42)), partitionable random-bits mode:
// bits[i] = out0 ^ out1 of threefry2x32((0,42), (hi=0, lo=i))
// uniform = bitcast((bits>>9)|0x3f800000) - 1.0 ; bern = uniform < 0.3f
// ---------------------------------------------------------------------------
__device__ __forceinline__ unsigned rotl32(unsigned x, int r) {
    return (x << r) | (x >> (32 - r));
}

__device__ __forceinline__ bool bern_hit(unsigned idx) {
    const unsigned ks0 = 0u;
    const unsigned ks1 = 42u;
    const unsigned ks2 = 0x1BD11BDAu ^ 0u ^ 42u;
    unsigned x0 = ks0;        // counts_hi (=0) + ks0
    unsigned x1 = idx + ks1;  // counts_lo (=i) + ks1
#define TFR(r) { x0 += x1; x1 = rotl32(x1, (r)); x1 ^= x0; }
    TFR(13) TFR(15) TFR(26) TFR(6)   x0 += ks1; x1 += ks2 + 1u;
    TFR(17) TFR(29) TFR(16) TFR(24)  x0 += ks2; x1 += ks0 + 2u;
    TFR(13) TFR(15) TFR(26) TFR(6)   x0 += ks0; x1 += ks1 + 3u;
    TFR(17) TFR(29) TFR(16) TFR(24)  x0 += ks1; x1 += ks2 + 4u;
    TFR(13) TFR(15) TFR(26) TFR(6)   x0 += ks2; x1 += ks0 + 5u;
#undef TFR
    unsigned bits = x0 ^ x1;
    float u = __uint_as_float((bits >> 9) | 0x3f800000u) - 1.0f;
    return u < 0.3f;
}

// ---------------------------------------------------------------------------
// Mask canonicalization: the reference `mask` is a bool array; the upload
// dtype is ambiguous. Detect uint8 / int32 / int64 / float32 from the raw
// words and write a canonical int32 0/1 array of 4096 entries.
// ---------------------------------------------------------------------------
__global__ void prep_mask_kernel(const unsigned* __restrict__ mraw,
                                 int* __restrict__ mcanon) {
    __shared__ int f_gt1, f_nonfloatish, f_oddnz;
    const int t = threadIdx.x;  // blockDim.x == 1024
    if (t == 0) { f_gt1 = 0; f_nonfloatish = 0; f_oddnz = 0; }
    __syncthreads();
    unsigned w = mraw[t];  // first 4KB: safe under every candidate dtype
    if (w > 1u) f_gt1 = 1;
    if (w != 0u && w != 1u && w != 0x3f800000u) f_nonfloatish = 1;
    if ((t & 1) && w != 0u) f_oddnz = 1;
    __syncthreads();
    int mode;  // 0=int32, 1=uint8, 2=float32, 3=int64
    if (!f_gt1)                mode = f_oddnz ? 0 : 3;
    else if (!f_nonfloatish)   mode = 2;
    else                       mode = 1;

    for (int i = t; i < 4096; i += 1024) {
        int v;
        if (mode == 0)      v = (int)mraw[i];
        else if (mode == 1) v = ((const unsigned char*)mraw)[i] ? 1 : 0;
        else if (mode == 2) v = (mraw[i] != 0u) ? 1 : 0;
        else                v = (mraw[2 * i] != 0u) ? 1 : 0;
        mcanon[i] = v;
    }
}

// ---------------------------------------------------------------------------
// f32 GEMM: C[M,N] = relu(A[M,K] @ B[K,N] + bias[N]); 64x64 tile, BK=16
// ---------------------------------------------------------------------------
__global__ __launch_bounds__(256) void gemm_bias_relu(
    const float* __restrict__ A, const float* __restrict__ B,
    const float* __restrict__ bias, float* __restrict__ C,
    int M, int N, int K) {
    __shared__ float As[16][68];  // [k][m], padded to break bank conflicts
    __shared__ float Bs[16][68];  // [k][n]
    const int t  = threadIdx.x;
    const int tx = t & 15, ty = t >> 4;
    const int m0 = blockIdx.y * 64, n0 = blockIdx.x * 64;
    const int lr = t >> 2,  lk = (t & 3) * 4;   // A-tile loader
    const int bk = t >> 4,  bn = (t & 15) * 4;  // B-tile loader
    float acc[4][4] = {{0.f}};

    for (int k0 = 0; k0 < K; k0 += 16) {
        float4 av = *reinterpret_cast<const float4*>(&A[(size_t)(m0 + lr) * K + k0 + lk]);
        float4 bv = *reinterpret_cast<const float4*>(&B[(size_t)(k0 + bk) * N + n0 + bn]);
        __syncthreads();
        As[lk + 0][lr] = av.x; As[lk + 1][lr] = av.y;
        As[lk + 2][lr] = av.z; As[lk + 3][lr] = av.w;
        *reinterpret_cast<float4*>(&Bs[bk][bn]) = bv;
        __syncthreads();
#pragma unroll
        for (int kk = 0; kk < 16; ++kk) {
            float4 a  = *reinterpret_cast<const float4*>(&As[kk][ty * 4]);
            float4 bq = *reinterpret_cast<const float4*>(&Bs[kk][tx * 4]);
            float ar[4] = {a.x, a.y, a.z, a.w};
            float br[4] = {bq.x, bq.y, bq.z, bq.w};
#pragma unroll
            for (int i = 0; i < 4; ++i)
#pragma unroll
                for (int j = 0; j < 4; ++j)
                    acc[i][j] = fmaf(ar[i], br[j], acc[i][j]);
        }
    }
#pragma unroll
    for (int i = 0; i < 4; ++i) {
        const int m = m0 + ty * 4 + i, n = n0 + tx * 4;
        float4 o;
        o.x = fmaxf(acc[i][0] + bias[n + 0], 0.f);
        o.y = fmaxf(acc[i][1] + bias[n + 1], 0.f);
        o.z = fmaxf(acc[i][2] + bias[n + 2], 0.f);
        o.w = fmaxf(acc[i][3] + bias[n + 3], 0.f);
        *reinterpret_cast<float4*>(&C[(size_t)m * N + n]) = o;
    }
}

// ---------------------------------------------------------------------------
// Attention: one block (256 thr) per (b, h, q) row.
//   logits[k] = (keymask[k] || causal) ? -1e9
//             : dot(q,k)/8 + pos[b,q,k] + bern*(-1e9)
//   full 1024-wide softmax (masked entries participate — exact JAX semantics),
//   then out[b,q,h,d] = sum_k p[k] * v[b,k,h,d]
// ---------------------------------------------------------------------------
__global__ __launch_bounds__(256) void attn_kernel(
    const float* __restrict__ Qm, const float* __restrict__ Km,
    const float* __restrict__ Vm, const float* __restrict__ pos,
    const int* __restrict__ mcanon, const unsigned* __restrict__ dec,
    float* __restrict__ Om) {
    const int qi = blockIdx.x, h = blockIdx.y, b = blockIdx.z;
    const int t = threadIdx.x;
    __shared__ float s[1024];
    __shared__ float qs[64];
    __shared__ float red[256];

    const int dm = (dec[0] != 0u);

    if (t < 64) qs[t] = Qm[((size_t)(b * 1024 + qi)) * 1024 + h * 64 + t];
    __syncthreads();

    const float* Kb = &Km[((size_t)b * 1024) * 1024 + h * 64];
    const float* posrow = &pos[((size_t)(b * 1024 + qi)) * 1024];
    const unsigned base_idx = (((unsigned)(b * 16 + h) * 1024u) + (unsigned)qi) * 1024u;
    const float4* q4 = reinterpret_cast<const float4*>(qs);

#pragma unroll
    for (int c = 0; c < 4; ++c) {
        const int ki = t + 256 * c;
        float logit = NEGV;
        const bool kmask  = (mcanon[b * 1024 + ki] != 0);
        const bool causal = dm && (ki > qi);
        if (!kmask && !causal) {
            const float4* kr = reinterpret_cast<const float4*>(&Kb[(size_t)ki * 1024]);
            float dot = 0.f;
#pragma unroll
            for (int d4 = 0; d4 < 16; ++d4) {
                float4 kv = kr[d4], qv = q4[d4];
                dot = fmaf(kv.x, qv.x, dot);
                dot = fmaf(kv.y, qv.y, dot);
                dot = fmaf(kv.z, qv.z, dot);
                dot = fmaf(kv.w, qv.w, dot);
            }
            float sc = dot * 0.125f + posrow[ki];
            if (bern_hit(base_idx + (unsigned)ki)) sc += NEGV;
            logit = sc;
        }
        s[ki] = logit;
    }
    __syncthreads();

    // row max
    float pm = fmaxf(fmaxf(s[t], s[t + 256]), fmaxf(s[t + 512], s[t + 768]));
    red[t] = pm;
    __syncthreads();
    for (int st = 128; st >= 1; st >>= 1) {
        if (t < st) red[t] = fmaxf(red[t], red[t + st]);
        __syncthreads();
    }
    const float mx = red[0];
    __syncthreads();

    // exp + sum
    float psum = 0.f;
#pragma unroll
    for (int c = 0; c < 4; ++c) {
        const int ki = t + 256 * c;
        float e = expf(s[ki] - mx);
        s[ki] = e;
        psum += e;
    }
    red[t] = psum;
    __syncthreads();
    for (int st = 128; st >= 1; st >>= 1) {
        if (t < st) red[t] += red[t + st];
        __syncthreads();
    }
    const float inv = 1.0f / red[0];
    __syncthreads();

    // PV: thread (d = t&63, c4 = t>>6) accumulates ki = c4 + 4*j
    const int d = t & 63, c4 = t >> 6;
    const float* Vb = &Vm[((size_t)b * 1024) * 1024 + h * 64 + d];
    float acc = 0.f;
#pragma unroll 4
    for (int j = 0; j < 256; ++j) {
        const int ki = c4 + 4 * j;
        acc = fmaf(s[ki], Vb[(size_t)ki * 1024], acc);
    }
    red[t] = acc;
    __syncthreads();
    if (t < 64) {
        float o = (red[t] + red[t + 64] + red[t + 128] + red[t + 192]) * inv;
        Om[((size_t)(b * 1024 + qi)) * 1024 + h * 64 + t] = o;
    }
}

// ---------------------------------------------------------------------------
extern "C" void kernel_launch(void* const* d_in, const int* in_sizes, int n_in,
                              void* d_out, int out_size, void* d_ws, size_t ws_size,
                              hipStream_t stream) {
    const float* x    = (const float*)d_in[0];
    const unsigned* mraw = (const unsigned*)d_in[1];
    const float* pos  = (const float*)d_in[2];
    const unsigned* dec = (const unsigned*)d_in[3];
    const float* Wq = (const float*)d_in[4];  const float* bq = (const float*)d_in[5];
    const float* Wk = (const float*)d_in[6];  const float* bk = (const float*)d_in[7];
    const float* Wv = (const float*)d_in[8];  const float* bv = (const float*)d_in[9];
    const float* Wo = (const float*)d_in[10]; const float* bo = (const float*)d_in[11];
    float* out = (float*)d_out;

    const size_t NM = 4096ull * 1024ull;  // 4,194,304 floats per [4096,1024] buffer
    float* Q  = (float*)d_ws;
    float* K  = Q + NM;
    float* V  = K + NM;
    float* AO = V + NM;
    int* mcanon = (int*)(AO + NM);

    prep_mask_kernel<<<1, 1024, 0, stream>>>(mraw, mcanon);

    dim3 gg(16, 64);  // N/64, M/64
    gemm_bias_relu<<<gg, 256, 0, stream>>>(x, Wq, bq, Q, 4096, 1024, 1024);
    gemm_bias_relu<<<gg, 256, 0, stream>>>(x, Wk, bk, K, 4096, 1024, 1024);
    gemm_bias_relu<<<gg, 256, 0, stream>>>(x, Wv, bv, V, 4096, 1024, 1024);

    attn_kernel<<<dim3(1024, 16, 4), 256, 0, stream>>>(Q, K, V, pos, mcanon, dec, AO);

    gemm_bias_relu<<<gg, 256, 0, stream>>>(AO, Wo, bo, out, 4096, 1024, 1024);
}

// Round 2
// 437.937 us; speedup vs baseline: 4.9420x; 4.9420x over previous
//
#include <hip/hip_runtime.h>
#include <hip/hip_bf16.h>

#define NEGV (-1e9f)

typedef __attribute__((ext_vector_type(4))) float f32x4;
typedef __attribute__((ext_vector_type(8))) short short8;

#define MFMA_BF16(a, b, c) __builtin_amdgcn_mfma_f32_16x16x32_bf16((a), (b), (c), 0, 0, 0)

#define GLOAD_LDS16(gsrc, ldst)                                                        \
    __builtin_amdgcn_global_load_lds(                                                  \
        (const __attribute__((address_space(1))) unsigned int*)(gsrc),                 \
        (__attribute__((address_space(3))) unsigned int*)(ldst), 16, 0, 0)

__device__ __forceinline__ unsigned short f2bf(float f) {
    union { float f; unsigned u; } v; v.f = f;
    return (unsigned short)((v.u + 0x7fffu + ((v.u >> 16) & 1u)) >> 16);
}

__device__ __forceinline__ unsigned rotl32(unsigned x, int r) {
    return (x << r) | (x >> (32 - r));
}

// JAX threefry2x32 key=(0,42), partitionable mode — verified in round 1.
__device__ __forceinline__ bool bern_hit(unsigned idx) {
    const unsigned ks0 = 0u, ks1 = 42u, ks2 = 0x1BD11BDAu ^ 0u ^ 42u;
    unsigned x0 = ks0, x1 = idx + ks1;
#define TFR(r) { x0 += x1; x1 = rotl32(x1, (r)); x1 ^= x0; }
    TFR(13) TFR(15) TFR(26) TFR(6)   x0 += ks1; x1 += ks2 + 1u;
    TFR(17) TFR(29) TFR(16) TFR(24)  x0 += ks2; x1 += ks0 + 2u;
    TFR(13) TFR(15) TFR(26) TFR(6)   x0 += ks0; x1 += ks1 + 3u;
    TFR(17) TFR(29) TFR(16) TFR(24)  x0 += ks1; x1 += ks2 + 4u;
    TFR(13) TFR(15) TFR(26) TFR(6)   x0 += ks2; x1 += ks0 + 5u;
#undef TFR
    unsigned bits = x0 ^ x1;
    float u = __uint_as_float((bits >> 9) | 0x3f800000u) - 1.0f;
    return u < 0.3f;
}

// ---------------------------------------------------------------------------
// Mask canonicalization (dtype detection) — unchanged from round 1 (verified).
// ---------------------------------------------------------------------------
__global__ void prep_mask_kernel(const unsigned* __restrict__ mraw,
                                 int* __restrict__ mcanon) {
    __shared__ int f_gt1, f_nonfloatish, f_oddnz;
    const int t = threadIdx.x;  // 1024
    if (t == 0) { f_gt1 = 0; f_nonfloatish = 0; f_oddnz = 0; }
    __syncthreads();
    unsigned w = mraw[t];
    if (w > 1u) f_gt1 = 1;
    if (w != 0u && w != 1u && w != 0x3f800000u) f_nonfloatish = 1;
    if ((t & 1) && w != 0u) f_oddnz = 1;
    __syncthreads();
    int mode;  // 0=int32, 1=uint8, 2=float32, 3=int64
    if (!f_gt1)              mode = f_oddnz ? 0 : 3;
    else if (!f_nonfloatish) mode = 2;
    else                     mode = 1;
    for (int i = t; i < 4096; i += 1024) {
        int v;
        if (mode == 0)      v = (int)mraw[i];
        else if (mode == 1) v = ((const unsigned char*)mraw)[i] ? 1 : 0;
        else if (mode == 2) v = (mraw[i] != 0u) ? 1 : 0;
        else                v = (mraw[2 * i] != 0u) ? 1 : 0;
        mcanon[i] = v;
    }
}

// ---------------------------------------------------------------------------
// f32 -> bf16 elementwise (x). 4 elems/thread.
// ---------------------------------------------------------------------------
__global__ __launch_bounds__(256) void conv_x_kernel(const float* __restrict__ in,
                                                     unsigned short* __restrict__ out) {
    const int i = (blockIdx.x * 256 + threadIdx.x) * 4;
    float4 v = *reinterpret_cast<const float4*>(&in[i]);
    ushort4 o;
    o.x = f2bf(v.x); o.y = f2bf(v.y); o.z = f2bf(v.z); o.w = f2bf(v.w);
    *reinterpret_cast<ushort4*>(&out[i]) = o;
}

// ---------------------------------------------------------------------------
// W [K=1024][N=1024] f32  ->  WT [N][K] bf16 (transpose + convert), 64x64 tiles
// ---------------------------------------------------------------------------
__global__ __launch_bounds__(256) void conv_wt_kernel(const float* __restrict__ W,
                                                      unsigned short* __restrict__ WT) {
    __shared__ float ts[64][68];
    const int t = threadIdx.x;
    const int k0 = blockIdx.y * 64, n0 = blockIdx.x * 64;
    const int r = t >> 4, c4 = (t & 15) * 4;
#pragma unroll
    for (int rr = 0; rr < 4; ++rr) {
        const int row = r + rr * 16;
        float4 v = *reinterpret_cast<const float4*>(&W[(size_t)(k0 + row) * 1024 + n0 + c4]);
        ts[row][c4 + 0] = v.x; ts[row][c4 + 1] = v.y;
        ts[row][c4 + 2] = v.z; ts[row][c4 + 3] = v.w;
    }
    __syncthreads();
#pragma unroll
    for (int rr = 0; rr < 4; ++rr) {
        const int n = r + rr * 16;
        ushort4 o;
        o.x = f2bf(ts[c4 + 0][n]); o.y = f2bf(ts[c4 + 1][n]);
        o.z = f2bf(ts[c4 + 2][n]); o.w = f2bf(ts[c4 + 3][n]);
        *reinterpret_cast<ushort4*>(&WT[(size_t)(n0 + n) * 1024 + k0 + c4]) = o;
    }
}

// ---------------------------------------------------------------------------
// bf16 MFMA GEMM: C = relu(A[M,K] @ W + bias), W given as BT[N][K] bf16.
// 128x128 tile, BK=64, 4 waves (2x2 of 64x64). XOR-swizzled LDS (rule #21:
// linear gload_lds dest + pre-swizzled global source + swizzled ds_read).
// ---------------------------------------------------------------------------
template<int WRITE_BF16>
__global__ __launch_bounds__(256) void gemm_bf16(
    const unsigned short* __restrict__ A, const unsigned short* __restrict__ BT,
    const float* __restrict__ bias, void* __restrict__ Cout,
    int M, int N, int K) {
    __shared__ unsigned short As[8192];  // 128 rows x 64 bf16 (128B rows)
    __shared__ unsigned short Bs[8192];
    const int t = threadIdx.x;
    const int lane = t & 63, w = t >> 6;
    const int wr = w >> 1, wc = w & 1;
    const int lgrp = lane >> 4, l15 = lane & 15;
    const int m0 = blockIdx.y * 128, n0 = blockIdx.x * 128;
    const int srow = t >> 3;                       // 0..31
    const int scol = ((t & 7) ^ (srow & 7)) << 3;  // pre-swizzled source col (bf16)
    const int rdsw = (l15 & 7) << 4;               // read-side XOR
    f32x4 acc[4][4] = {};

    for (int k0 = 0; k0 < K; k0 += 64) {
#pragma unroll
        for (int s = 0; s < 4; ++s) {
            GLOAD_LDS16(&A[(size_t)(m0 + s * 32 + srow) * K + (k0 + scol)], &As[s * 2048 + t * 8]);
            GLOAD_LDS16(&BT[(size_t)(n0 + s * 32 + srow) * K + (k0 + scol)], &Bs[s * 2048 + t * 8]);
        }
        __syncthreads();
#pragma unroll
        for (int kkh = 0; kkh < 2; ++kkh) {
            const int klb = (kkh * 32 + (lgrp << 3)) * 2;  // byte offset of k within row
            short8 af[4], bf[4];
#pragma unroll
            for (int i = 0; i < 4; ++i) {
                af[i] = *(const short8*)((const char*)As + (wr * 64 + i * 16 + l15) * 128 + (klb ^ rdsw));
                bf[i] = *(const short8*)((const char*)Bs + (wc * 64 + i * 16 + l15) * 128 + (klb ^ rdsw));
            }
#pragma unroll
            for (int mf = 0; mf < 4; ++mf)
#pragma unroll
                for (int nf = 0; nf < 4; ++nf)
                    acc[mf][nf] = MFMA_BF16(af[mf], bf[nf], acc[mf][nf]);
        }
        __syncthreads();
    }
#pragma unroll
    for (int nf = 0; nf < 4; ++nf) {
        const int n = n0 + wc * 64 + nf * 16 + l15;
        const float bv = bias[n];
#pragma unroll
        for (int mf = 0; mf < 4; ++mf) {
#pragma unroll
            for (int r = 0; r < 4; ++r) {
                const int m = m0 + wr * 64 + mf * 16 + (lgrp << 2) + r;
                float v = fmaxf(acc[mf][nf][r] + bv, 0.f);
                if (WRITE_BF16) ((unsigned short*)Cout)[(size_t)m * N + n] = f2bf(v);
                else            ((float*)Cout)[(size_t)m * N + n] = v;
            }
        }
    }
}

// ---------------------------------------------------------------------------
// Flash-style attention. Block = 256 thr (4 waves), 64 q-rows of one (b,h).
// Swapped QK^T (A=K, B=Q -> S^T), f32 logits w/ exact -1e9 semantics, online
// softmax via LDS, PV via MFMA with reg-transposed V^T tile.
// ---------------------------------------------------------------------------
__global__ __launch_bounds__(256) void attn_kernel(
    const unsigned short* __restrict__ Qb, const unsigned short* __restrict__ Kb,
    const unsigned short* __restrict__ Vb, const float* __restrict__ pos,
    const int* __restrict__ mcanon, const unsigned* __restrict__ dec,
    unsigned short* __restrict__ AO) {
    const int q0 = blockIdx.x * 64, h = blockIdx.y, b = blockIdx.z;
    const int t = threadIdx.x, lane = t & 63, w = t >> 6;
    const int lgrp = lane >> 4, l15 = lane & 15;

    __shared__ unsigned short Ks[4096];  // [key][d] 64x64 bf16, swizzled
    __shared__ unsigned short VT[4096];  // [d][key] 64x64 bf16, swizzled
    __shared__ float Sb[4096];           // S^T [key][q] f32, swizzled; P aliases low half
    __shared__ float m_s[64], l_s[64], fac_s[64], mn_s[64];
    __shared__ float red[256];
    unsigned short* Pb = reinterpret_cast<unsigned short*>(Sb);  // [q][key] bf16

    const int dm = (dec[0] != 0u) ? 1 : 0;
    if (t < 64) { m_s[t] = -3e38f; l_s[t] = 0.f; }

    // Q fragments in registers: q = q0 + w*16 + l15, d = lgrp*8 (+32)
    const int qi = q0 + w * 16 + l15;
    const size_t qg = ((size_t)(b * 1024 + qi)) * 1024 + h * 64 + (lgrp << 3);
    const short8 qb0 = *(const short8*)&Qb[qg];
    const short8 qb1 = *(const short8*)&Qb[qg + 32];

    f32x4 osc[4] = {};  // O accumulator: 4 d-frags, rows q = w*16 + lgrp*4 + r
    const int qor = w * 16 + (lgrp << 2);
    const int sq = t & 63, kq = t >> 6;  // softmax-phase ownership

    __syncthreads();

    for (int kt = 0; kt < 16; ++kt) {
        const int kbase = kt * 64;
        const bool tlive = (!dm) || (kbase <= q0 + 63);

        // ---- stage K (global_load_lds, pre-swizzled source) ----
        if (tlive) {
            const int srow = t >> 3;
            const int scol = ((t & 7) ^ (srow & 7)) << 3;
#pragma unroll
            for (int s = 0; s < 2; ++s) {
                GLOAD_LDS16(&Kb[((size_t)(b * 1024 + kbase + s * 32 + srow)) * 1024 + h * 64 + scol],
                            &Ks[s * 2048 + t * 8]);
            }
        }
        // ---- stage V^T (register transpose, swizzled scalar writes) ----
        {
            const int key = t >> 2, dblk = (t & 3) << 4;
            const unsigned short* vsrc = &Vb[((size_t)(b * 1024 + kbase + key)) * 1024 + h * 64 + dblk];
            short8 v0 = *(const short8*)vsrc;
            short8 v1 = *(const short8*)(vsrc + 8);
#pragma unroll
            for (int j = 0; j < 8; ++j) {
                const int d = dblk + j;
                const int sw = (d & 7) ^ ((d >> 3) & 7);
                *(unsigned short*)((char*)VT + d * 128 + (((key >> 3) ^ sw) << 4) + ((key & 7) << 1)) =
                    (unsigned short)v0[j];
            }
#pragma unroll
            for (int j = 0; j < 8; ++j) {
                const int d = dblk + 8 + j;
                const int sw = (d & 7) ^ ((d >> 3) & 7);
                *(unsigned short*)((char*)VT + d * 128 + (((key >> 3) ^ sw) << 4) + ((key & 7) << 1)) =
                    (unsigned short)v1[j];
            }
        }
        __syncthreads();  // A: tiles staged

        // ---- QK^T (S^T = K @ Q^T) ----
        f32x4 sacc[4] = {};
        if (tlive) {
#pragma unroll
            for (int kkh = 0; kkh < 2; ++kkh) {
                const int klb = (kkh * 32 + (lgrp << 3)) * 2;
                const short8 qf = kkh ? qb1 : qb0;
#pragma unroll
                for (int f = 0; f < 4; ++f) {
                    short8 kf = *(const short8*)((const char*)Ks + (f * 16 + l15) * 128 +
                                                 (klb ^ ((l15 & 7) << 4)));
                    sacc[f] = MFMA_BF16(kf, qf, sacc[f]);
                }
            }
        }

        // ---- logits: scale + pos + bern + masks; store S^T to LDS ----
#pragma unroll
        for (int f = 0; f < 4; ++f) {
#pragma unroll
            for (int r = 0; r < 4; ++r) {
                const int keyl = f * 16 + (lgrp << 2) + r;
                const int ki = kbase + keyl;
                float logit = NEGV;
                if (tlive) {
                    const bool km = (mcanon[b * 1024 + ki] != 0);
                    const bool cz = dm && (ki > qi);
                    if (!km && !cz) {
                        float sc = sacc[f][r] * 0.125f + pos[((size_t)(b * 1024 + qi)) * 1024 + ki];
                        if (bern_hit((((unsigned)((b * 16 + h) * 1024 + qi)) << 10) + (unsigned)ki))
                            sc += NEGV;
                        logit = sc;
                    }
                }
                const int qloc = w * 16 + l15;
                *(float*)((char*)Sb + keyl * 256 + ((qloc * 4) ^ (((keyl >> 2) & 3) << 6))) = logit;
            }
        }
        __syncthreads();  // B: S^T complete

        // ---- softmax (thread t: q = sq, keys kq*16..+15) ----
        float sreg[16];
        float lmax = -3e38f;
#pragma unroll
        for (int j = 0; j < 16; ++j) {
            const int keyl = kq * 16 + j;
            float v = *(const float*)((const char*)Sb + keyl * 256 +
                                      ((sq * 4) ^ (((keyl >> 2) & 3) << 6)));
            sreg[j] = v;
            lmax = fmaxf(lmax, v);
        }
        red[t] = lmax;
        __syncthreads();  // C
        if (t < 64) {
            const float mt = fmaxf(fmaxf(red[t], red[t + 64]), fmaxf(red[t + 128], red[t + 192]));
            const float mo = m_s[t];
            const float mn = fmaxf(mo, mt);
            mn_s[t] = mn;
            fac_s[t] = expf(mo - mn);
            m_s[t] = mn;
        }
        __syncthreads();  // D: mn/fac ready (Sb reads all done -> P may overwrite)

        const float mn = mn_s[sq];
        float psum = 0.f;
        unsigned short pbv[16];
#pragma unroll
        for (int j = 0; j < 16; ++j) {
            float p = expf(sreg[j] - mn);
            psum += p;
            pbv[j] = f2bf(p);
        }
        {   // write P [q][key] bf16, swizzled, 2 x b128
            short8 w0, w1;
#pragma unroll
            for (int j = 0; j < 8; ++j) { w0[j] = (short)pbv[j]; w1[j] = (short)pbv[j + 8]; }
            const int sw = sq & 7;
            *(short8*)((char*)Pb + sq * 128 + (((kq * 2) ^ sw) << 4)) = w0;
            *(short8*)((char*)Pb + sq * 128 + (((kq * 2 + 1) ^ sw) << 4)) = w1;
        }
        red[t] = psum;
        __syncthreads();  // E: P + psum ready
        if (t < 64) {
            const float ps = red[t] + red[t + 64] + red[t + 128] + red[t + 192];
            l_s[t] = l_s[t] * fac_s[t] + ps;
        }

        // ---- PV: rescale O, then O += P @ V ----
        {
            float fr[4];
#pragma unroll
            for (int r = 0; r < 4; ++r) fr[r] = fac_s[qor + r];
#pragma unroll
            for (int nf = 0; nf < 4; ++nf)
#pragma unroll
                for (int r = 0; r < 4; ++r) osc[nf][r] *= fr[r];
#pragma unroll
            for (int kkh = 0; kkh < 2; ++kkh) {
                short8 pa = *(const short8*)((const char*)Pb + (w * 16 + l15) * 128 +
                                             (((kkh * 32 + (lgrp << 3)) * 2) ^ ((l15 & 7) << 4)));
#pragma unroll
                for (int nf = 0; nf < 4; ++nf) {
                    const int d = nf * 16 + l15;
                    const int sw = (d & 7) ^ ((d >> 3) & 7);
                    short8 vf = *(const short8*)((const char*)VT + d * 128 +
                                                 (((kkh * 4 + lgrp) ^ sw) << 4));
                    osc[nf] = MFMA_BF16(pa, vf, osc[nf]);
                }
            }
        }
        __syncthreads();  // F: end of tile (protects Ks/VT/Sb/l_s)
    }

    // ---- epilogue: normalize, write AO bf16 ----
    float invl[4];
#pragma unroll
    for (int r = 0; r < 4; ++r) invl[r] = 1.0f / l_s[qor + r];
#pragma unroll
    for (int nf = 0; nf < 4; ++nf) {
#pragma unroll
        for (int r = 0; r < 4; ++r) {
            const int qi2 = q0 + qor + r;
            const int dg = nf * 16 + l15;
            AO[((size_t)(b * 1024 + qi2)) * 1024 + h * 64 + dg] = f2bf(osc[nf][r] * invl[r]);
        }
    }
}

// ---------------------------------------------------------------------------
extern "C" void kernel_launch(void* const* d_in, const int* in_sizes, int n_in,
                              void* d_out, int out_size, void* d_ws, size_t ws_size,
                              hipStream_t stream) {
    const float* x      = (const float*)d_in[0];
    const unsigned* mraw = (const unsigned*)d_in[1];
    const float* pos    = (const float*)d_in[2];
    const unsigned* dec = (const unsigned*)d_in[3];
    const float* Wq = (const float*)d_in[4];  const float* bq = (const float*)d_in[5];
    const float* Wk = (const float*)d_in[6];  const float* bk = (const float*)d_in[7];
    const float* Wv = (const float*)d_in[8];  const float* bv = (const float*)d_in[9];
    const float* Wo = (const float*)d_in[10]; const float* bo = (const float*)d_in[11];
    float* out = (float*)d_out;

    char* ws = (char*)d_ws;
    unsigned short* xb  = (unsigned short*)(ws);                     // 8 MB
    unsigned short* wtq = (unsigned short*)(ws + (8u  << 20));       // 2 MB each
    unsigned short* wtk = (unsigned short*)(ws + (10u << 20));
    unsigned short* wtv = (unsigned short*)(ws + (12u << 20));
    unsigned short* wto = (unsigned short*)(ws + (14u << 20));
    unsigned short* Qb  = (unsigned short*)(ws + (16u << 20));       // 8 MB
    unsigned short* Kb  = (unsigned short*)(ws + (24u << 20));       // 8 MB
    unsigned short* Vb  = (unsigned short*)(ws + (32u << 20));       // 8 MB
    unsigned short* AO  = (unsigned short*)(ws + (40u << 20));       // 8 MB
    int* mcanon         = (int*)(ws + (48u << 20));                  // 16 KB

    prep_mask_kernel<<<1, 1024, 0, stream>>>(mraw, mcanon);
    conv_x_kernel<<<4096, 256, 0, stream>>>(x, xb);
    dim3 tg(16, 16);
    conv_wt_kernel<<<tg, 256, 0, stream>>>(Wq, wtq);
    conv_wt_kernel<<<tg, 256, 0, stream>>>(Wk, wtk);
    conv_wt_kernel<<<tg, 256, 0, stream>>>(Wv, wtv);
    conv_wt_kernel<<<tg, 256, 0, stream>>>(Wo, wto);

    dim3 gg(8, 32);  // N/128, M/128
    gemm_bf16<1><<<gg, 256, 0, stream>>>(xb, wtq, bq, Qb, 4096, 1024, 1024);
    gemm_bf16<1><<<gg, 256, 0, stream>>>(xb, wtk, bk, Kb, 4096, 1024, 1024);
    gemm_bf16<1><<<gg, 256, 0, stream>>>(xb, wtv, bv, Vb, 4096, 1024, 1024);

    attn_kernel<<<dim3(16, 16, 4), 256, 0, stream>>>(Qb, Kb, Vb, pos, mcanon, dec, AO);

    gemm_bf16<0><<<gg, 256, 0, stream>>>(AO, wto, bo, out, 4096, 1024, 1024);
}

// Round 3
// 331.859 us; speedup vs baseline: 6.5217x; 1.3196x over previous
//
#include <hip/hip_runtime.h>
#include <hip/hip_bf16.h>

#define NEGV (-1e9f)

typedef __attribute__((ext_vector_type(4))) float f32x4;
typedef __attribute__((ext_vector_type(8))) short short8;

#define MFMA_BF16(a, b, c) __builtin_amdgcn_mfma_f32_16x16x32_bf16((a), (b), (c), 0, 0, 0)

#define GLOAD_LDS16(gsrc, ldst)                                                        \
    __builtin_amdgcn_global_load_lds(                                                  \
        (const __attribute__((address_space(1))) unsigned int*)(gsrc),                 \
        (__attribute__((address_space(3))) unsigned int*)(ldst), 16, 0, 0)

#define GLOAD_LDS4(gsrc, ldst)                                                         \
    __builtin_amdgcn_global_load_lds(                                                  \
        (const __attribute__((address_space(1))) unsigned int*)(gsrc),                 \
        (__attribute__((address_space(3))) unsigned int*)(ldst), 4, 0, 0)

__device__ __forceinline__ unsigned short f2bf(float f) {
    union { float f; unsigned u; } v; v.f = f;
    return (unsigned short)((v.u + 0x7fffu + ((v.u >> 16) & 1u)) >> 16);
}

__device__ __forceinline__ float bf2f(unsigned short u) {
    return __uint_as_float((unsigned)u << 16);
}

__device__ __forceinline__ unsigned rotl32(unsigned x, int r) {
    return (x << r) | (x >> (32 - r));
}

// JAX threefry2x32 key=(0,42), partitionable mode — verified round 1.
__device__ __forceinline__ bool bern_hit(unsigned idx) {
    const unsigned ks0 = 0u, ks1 = 42u, ks2 = 0x1BD11BDAu ^ 0u ^ 42u;
    unsigned x0 = ks0, x1 = idx + ks1;
#define TFR(r) { x0 += x1; x1 = rotl32(x1, (r)); x1 ^= x0; }
    TFR(13) TFR(15) TFR(26) TFR(6)   x0 += ks1; x1 += ks2 + 1u;
    TFR(17) TFR(29) TFR(16) TFR(24)  x0 += ks2; x1 += ks0 + 2u;
    TFR(13) TFR(15) TFR(26) TFR(6)   x0 += ks0; x1 += ks1 + 3u;
    TFR(17) TFR(29) TFR(16) TFR(24)  x0 += ks1; x1 += ks2 + 4u;
    TFR(13) TFR(15) TFR(26) TFR(6)   x0 += ks2; x1 += ks0 + 5u;
#undef TFR
    unsigned bits = x0 ^ x1;
    float u = __uint_as_float((bits >> 9) | 0x3f800000u) - 1.0f;
    return u < 0.3f;
}

// ---------------------------------------------------------------------------
// Mask canonicalization (dtype detection) — verified round 1.
// ---------------------------------------------------------------------------
__global__ void prep_mask_kernel(const unsigned* __restrict__ mraw,
                                 int* __restrict__ mcanon) {
    __shared__ int f_gt1, f_nonfloatish, f_oddnz;
    const int t = threadIdx.x;  // 1024
    if (t == 0) { f_gt1 = 0; f_nonfloatish = 0; f_oddnz = 0; }
    __syncthreads();
    unsigned w = mraw[t];
    if (w > 1u) f_gt1 = 1;
    if (w != 0u && w != 1u && w != 0x3f800000u) f_nonfloatish = 1;
    if ((t & 1) && w != 0u) f_oddnz = 1;
    __syncthreads();
    int mode;  // 0=int32, 1=uint8, 2=float32, 3=int64
    if (!f_gt1)              mode = f_oddnz ? 0 : 3;
    else if (!f_nonfloatish) mode = 2;
    else                     mode = 1;
    for (int i = t; i < 4096; i += 1024) {
        int v;
        if (mode == 0)      v = (int)mraw[i];
        else if (mode == 1) v = ((const unsigned char*)mraw)[i] ? 1 : 0;
        else if (mode == 2) v = (mraw[i] != 0u) ? 1 : 0;
        else                v = (mraw[2 * i] != 0u) ? 1 : 0;
        mcanon[i] = v;
    }
}

// ---------------------------------------------------------------------------
// f32 -> bf16 elementwise (x).
// ---------------------------------------------------------------------------
__global__ __launch_bounds__(256) void conv_x_kernel(const float* __restrict__ in,
                                                     unsigned short* __restrict__ out) {
    const int i = (blockIdx.x * 256 + threadIdx.x) * 4;
    float4 v = *reinterpret_cast<const float4*>(&in[i]);
    ushort4 o;
    o.x = f2bf(v.x); o.y = f2bf(v.y); o.z = f2bf(v.z); o.w = f2bf(v.w);
    *reinterpret_cast<ushort4*>(&out[i]) = o;
}

// ---------------------------------------------------------------------------
// W [K][N] f32 -> WT [N][K] bf16 (transpose + convert).
// ---------------------------------------------------------------------------
__global__ __launch_bounds__(256) void conv_wt_kernel(const float* __restrict__ W,
                                                      unsigned short* __restrict__ WT) {
    __shared__ float ts[64][68];
    const int t = threadIdx.x;
    const int k0 = blockIdx.y * 64, n0 = blockIdx.x * 64;
    const int r = t >> 4, c4 = (t & 15) * 4;
#pragma unroll
    for (int rr = 0; rr < 4; ++rr) {
        const int row = r + rr * 16;
        float4 v = *reinterpret_cast<const float4*>(&W[(size_t)(k0 + row) * 1024 + n0 + c4]);
        ts[row][c4 + 0] = v.x; ts[row][c4 + 1] = v.y;
        ts[row][c4 + 2] = v.z; ts[row][c4 + 3] = v.w;
    }
    __syncthreads();
#pragma unroll
    for (int rr = 0; rr < 4; ++rr) {
        const int n = r + rr * 16;
        ushort4 o;
        o.x = f2bf(ts[c4 + 0][n]); o.y = f2bf(ts[c4 + 1][n]);
        o.z = f2bf(ts[c4 + 2][n]); o.w = f2bf(ts[c4 + 3][n]);
        *reinterpret_cast<ushort4*>(&WT[(size_t)(n0 + n) * 1024 + k0 + c4]) = o;
    }
}

// ---------------------------------------------------------------------------
// bf16 MFMA GEMM: C = relu(A[M,K] @ W + bias), W as BT[N][K] bf16. Round-2 verified.
// ---------------------------------------------------------------------------
template<int WRITE_BF16>
__global__ __launch_bounds__(256) void gemm_bf16(
    const unsigned short* __restrict__ A, const unsigned short* __restrict__ BT,
    const float* __restrict__ bias, void* __restrict__ Cout,
    int M, int N, int K) {
    __shared__ unsigned short As[8192];
    __shared__ unsigned short Bs[8192];
    const int t = threadIdx.x;
    const int lane = t & 63, w = t >> 6;
    const int wr = w >> 1, wc = w & 1;
    const int lgrp = lane >> 4, l15 = lane & 15;
    const int m0 = blockIdx.y * 128, n0 = blockIdx.x * 128;
    const int srow = t >> 3;
    const int scol = ((t & 7) ^ (srow & 7)) << 3;
    const int rdsw = (l15 & 7) << 4;
    f32x4 acc[4][4] = {};

    for (int k0 = 0; k0 < K; k0 += 64) {
#pragma unroll
        for (int s = 0; s < 4; ++s) {
            GLOAD_LDS16(&A[(size_t)(m0 + s * 32 + srow) * K + (k0 + scol)], &As[s * 2048 + t * 8]);
            GLOAD_LDS16(&BT[(size_t)(n0 + s * 32 + srow) * K + (k0 + scol)], &Bs[s * 2048 + t * 8]);
        }
        __syncthreads();
#pragma unroll
        for (int kkh = 0; kkh < 2; ++kkh) {
            const int klb = (kkh * 32 + (lgrp << 3)) * 2;
            short8 af[4], bf[4];
#pragma unroll
            for (int i = 0; i < 4; ++i) {
                af[i] = *(const short8*)((const char*)As + (wr * 64 + i * 16 + l15) * 128 + (klb ^ rdsw));
                bf[i] = *(const short8*)((const char*)Bs + (wc * 64 + i * 16 + l15) * 128 + (klb ^ rdsw));
            }
#pragma unroll
            for (int mf = 0; mf < 4; ++mf)
#pragma unroll
                for (int nf = 0; nf < 4; ++nf)
                    acc[mf][nf] = MFMA_BF16(af[mf], bf[nf], acc[mf][nf]);
        }
        __syncthreads();
    }
#pragma unroll
    for (int nf = 0; nf < 4; ++nf) {
        const int n = n0 + wc * 64 + nf * 16 + l15;
        const float bv = bias[n];
#pragma unroll
        for (int mf = 0; mf < 4; ++mf) {
#pragma unroll
            for (int r = 0; r < 4; ++r) {
                const int m = m0 + wr * 64 + mf * 16 + (lgrp << 2) + r;
                float v = fmaxf(acc[mf][nf][r] + bv, 0.f);
                if (WRITE_BF16) ((unsigned short*)Cout)[(size_t)m * N + n] = f2bf(v);
                else            ((float*)Cout)[(size_t)m * N + n] = v;
            }
        }
    }
}

// ---------------------------------------------------------------------------
// V column means (for degenerate softmax rows: JAX gives uniform over ALL keys).
// ---------------------------------------------------------------------------
__global__ __launch_bounds__(256) void vsum_part(const unsigned short* __restrict__ Vb,
                                                 float* __restrict__ part) {
    const int c = blockIdx.x, b = blockIdx.y, t = threadIdx.x;
    float a0 = 0, a1 = 0, a2 = 0, a3 = 0;
    const unsigned short* src = &Vb[((size_t)(b * 1024 + c * 64)) * 1024 + t * 4];
    for (int r = 0; r < 64; ++r) {
        ushort4 v = *(const ushort4*)(src + (size_t)r * 1024);
        a0 += bf2f(v.x); a1 += bf2f(v.y); a2 += bf2f(v.z); a3 += bf2f(v.w);
    }
    float4 o = {a0, a1, a2, a3};
    *(float4*)&part[(size_t)(b * 16 + c) * 1024 + t * 4] = o;
}

__global__ __launch_bounds__(256) void vsum_reduce(const float* __restrict__ part,
                                                   float* __restrict__ vmean) {
    const int b = blockIdx.x, t = threadIdx.x;
    float4 s = {0, 0, 0, 0};
    for (int c = 0; c < 16; ++c) {
        float4 v = *(const float4*)&part[(size_t)(b * 16 + c) * 1024 + t * 4];
        s.x += v.x; s.y += v.y; s.z += v.z; s.w += v.w;
    }
    const float sc = 1.0f / 1024.0f;
    float4 o = {s.x * sc, s.y * sc, s.z * sc, s.w * sc};
    *(float4*)&vmean[b * 1024 + t * 4] = o;
}

// ---------------------------------------------------------------------------
// Flash attention, rewritten: paired q-tiles (uniform 17 k-tile iters/block),
// in-register online softmax (shfl_xor row reduce), ds_bpermute P redistribution,
// staged pos/mask tiles, packed-b32 V^T transpose, 2 barriers/tile,
// degenerate-row fixup via vmean.
// ---------------------------------------------------------------------------
__global__ __launch_bounds__(256) void attn_kernel(
    const unsigned short* __restrict__ Qb, const unsigned short* __restrict__ Kb,
    const unsigned short* __restrict__ Vb, const float* __restrict__ pos,
    const int* __restrict__ mcanon, const unsigned* __restrict__ dec,
    const float* __restrict__ vmean, unsigned short* __restrict__ AO) {
    const int g = blockIdx.x, h = blockIdx.y, b = blockIdx.z;
    const int t = threadIdx.x, lane = t & 63, w = t >> 6;
    const int lgrp = lane >> 4, l15 = lane & 15;

    __shared__ unsigned short Ks[4096];   // 64x64 bf16 [key][d], XOR-swizzled
    __shared__ unsigned short VT[4096];   // 64x64 bf16 [d][key], XOR-swizzled
    __shared__ float pos_s[4096];         // 64x64 f32 [qloc][key], granule-swizzled
    __shared__ int mask_s[64];

    const int dm = (dec[0] != 0u) ? 1 : 0;

    for (int ph = 0; ph < 2; ++ph) {
        const int qt = ph ? (15 - g) : g;
        const int q0 = qt * 64;
        const int ntiles = dm ? (qt + 1) : 16;
        const int qi = q0 + w * 16 + l15;

        const size_t qg = ((size_t)(b * 1024 + qi)) * 1024 + h * 64 + (lgrp << 3);
        const short8 qb0 = *(const short8*)&Qb[qg];
        const short8 qb1 = *(const short8*)&Qb[qg + 32];

        float m = -3e38f, l = 0.f;
        f32x4 osc[4] = {};

        for (int kt = 0; kt < ntiles; ++kt) {
            const int kbase = kt * 64;
            // ---- stage K (2 x gload16, pre-swizzled source) ----
            {
                const int srow = t >> 3;
                const int scol = ((t & 7) ^ (srow & 7)) << 3;
                GLOAD_LDS16(&Kb[((size_t)(b * 1024 + kbase + srow)) * 1024 + h * 64 + scol],
                            &Ks[t * 8]);
                GLOAD_LDS16(&Kb[((size_t)(b * 1024 + kbase + 32 + srow)) * 1024 + h * 64 + scol],
                            &Ks[2048 + t * 8]);
            }
            // ---- stage pos tile (4 x gload16/wave, granule swizzle c' = c ^ (row&15)) ----
#pragma unroll
            for (int s = 0; s < 4; ++s) {
                const int row = w * 16 + s * 4 + (lane >> 4);
                const int scol = ((lane & 15) ^ (row & 15)) << 2;
                GLOAD_LDS16(&pos[((size_t)(b * 1024 + q0 + row)) * 1024 + kbase + scol],
                            &pos_s[w * 1024 + s * 256 + lane * 4]);
            }
            // ---- stage mask (wave 0 only) ----
            if (w == 0) GLOAD_LDS4(&mcanon[b * 1024 + kbase + lane], &mask_s[lane]);
            // ---- stage V^T (packed b32 writes, 2-way-free banks) ----
            {
                const int p = t >> 3;            // key pair index 0..31
                const int dblk = (t & 7) << 3;   // d block of 8
                const unsigned short* vs = &Vb[((size_t)(b * 1024 + kbase + 2 * p)) * 1024 + h * 64 + dblk];
                short8 v0 = *(const short8*)vs;
                short8 v1 = *(const short8*)(vs + 1024);
#pragma unroll
                for (int j = 0; j < 8; ++j) {
                    const int d = dblk + j;
                    const int sw = (d & 7) ^ ((d >> 3) & 7);
                    unsigned word = (unsigned)(unsigned short)v0[j] |
                                    ((unsigned)(unsigned short)v1[j] << 16);
                    *(unsigned*)((char*)VT + d * 128 + ((((2 * p) >> 3) ^ sw) << 4) +
                                 (((2 * p) & 7) << 1)) = word;
                }
            }
            __syncthreads();  // A: all staging visible (compiler drains vmcnt+lgkmcnt)

            // ---- QK^T (swapped: S^T rows = keys, cols = q) ----
            f32x4 sacc[4] = {};
#pragma unroll
            for (int kkh = 0; kkh < 2; ++kkh) {
                const int klb = (kkh * 32 + (lgrp << 3)) * 2;
                const short8 qf = kkh ? qb1 : qb0;
#pragma unroll
                for (int f = 0; f < 4; ++f) {
                    short8 kf = *(const short8*)((const char*)Ks + (f * 16 + l15) * 128 +
                                                 (klb ^ ((l15 & 7) << 4)));
                    sacc[f] = MFMA_BF16(kf, qf, sacc[f]);
                }
            }

            // ---- logits (exact -1e9 semantics) + row max ----
            float p16[4][4];
            float tmax = -3e38f;
#pragma unroll
            for (int f = 0; f < 4; ++f) {
                const f32x4 posq = *(const f32x4*)&pos_s[(w * 16 + l15) * 64 +
                                                         (((f * 4 + lgrp) ^ l15) << 2)];
                const int4 mq = *(const int4*)&mask_s[f * 16 + (lgrp << 2)];
                const int mqa[4] = {mq.x, mq.y, mq.z, mq.w};
#pragma unroll
                for (int r = 0; r < 4; ++r) {
                    const int ki = kbase + f * 16 + (lgrp << 2) + r;
                    float lg = NEGV;
                    const bool live = (mqa[r] == 0) && !(dm && (ki > qi));
                    if (live) {
                        float sc = fmaf(sacc[f][r], 0.125f, posq[r]);
                        if (bern_hit((((unsigned)((b * 16 + h) * 1024 + qi)) << 10) + (unsigned)ki))
                            sc += NEGV;
                        lg = sc;
                    }
                    p16[f][r] = lg;
                    tmax = fmaxf(tmax, lg);
                }
            }
            tmax = fmaxf(tmax, __shfl_xor(tmax, 16, 64));
            tmax = fmaxf(tmax, __shfl_xor(tmax, 32, 64));
            const float mn = fmaxf(m, tmax);
            const float fac = expf(m - mn);

            // ---- P = exp(S - m), packed bf16 pairs; row sum ----
            float psum = 0.f;
            unsigned pk[4][2];
#pragma unroll
            for (int f = 0; f < 4; ++f) {
#pragma unroll
                for (int rr = 0; rr < 2; ++rr) {
                    float pa = expf(p16[f][2 * rr] - mn);
                    float pb = expf(p16[f][2 * rr + 1] - mn);
                    psum += pa + pb;
                    pk[f][rr] = (unsigned)f2bf(pa) | ((unsigned)f2bf(pb) << 16);
                }
            }
            psum += __shfl_xor(psum, 16, 64);
            psum += __shfl_xor(psum, 32, 64);
            l = l * fac + psum;
            m = mn;

            // ---- rescale O by fac (per C-row, via bpermute) ----
#pragma unroll
            for (int r = 0; r < 4; ++r) {
                const float fr = __int_as_float(__builtin_amdgcn_ds_bpermute(
                    (((lgrp << 2) + r) << 2), __float_as_int(fac)));
#pragma unroll
                for (int nf = 0; nf < 4; ++nf) osc[nf][r] *= fr;
            }

            // ---- redistribute P into A-fragments (ds_bpermute) + PV MFMA ----
            {
                const int idx0 = ((((lgrp << 1) & 3) << 4) | l15) << 2;
                const int idx1 = (((((lgrp << 1) + 1) & 3) << 4) | l15) << 2;
                const bool hi = (lgrp >> 1) != 0;
#pragma unroll
                for (int kkh = 0; kkh < 2; ++kkh) {
                    union { unsigned u[4]; short8 s; } pa;
#pragma unroll
                    for (int s2 = 0; s2 < 4; ++s2) {
                        const int rr = s2 & 1;
                        const int idx = (s2 >> 1) ? idx1 : idx0;
                        const unsigned lo = (unsigned)__builtin_amdgcn_ds_bpermute(idx, (int)pk[kkh * 2][rr]);
                        const unsigned hw = (unsigned)__builtin_amdgcn_ds_bpermute(idx, (int)pk[kkh * 2 + 1][rr]);
                        pa.u[s2] = hi ? hw : lo;
                    }
#pragma unroll
                    for (int nf = 0; nf < 4; ++nf) {
                        const int d = nf * 16 + l15;
                        const int sw = (d & 7) ^ ((d >> 3) & 7);
                        short8 vf = *(const short8*)((const char*)VT + d * 128 +
                                                     ((((kkh << 2) + lgrp) ^ sw) << 4));
                        osc[nf] = MFMA_BF16(pa.s, vf, osc[nf]);
                    }
                }
            }
            __syncthreads();  // B: all LDS reads done -> next tile may restage
        }

        // ---- epilogue: normalize (or degenerate fixup), write AO ----
#pragma unroll
        for (int r = 0; r < 4; ++r) {
            const int src = (((lgrp << 2) + r) << 2);
            const float lr = __int_as_float(__builtin_amdgcn_ds_bpermute(src, __float_as_int(l)));
            const float mr = __int_as_float(__builtin_amdgcn_ds_bpermute(src, __float_as_int(m)));
            const int qo = q0 + w * 16 + (lgrp << 2) + r;
            const bool dgen = (mr == NEGV);
            const float inv = 1.0f / lr;
#pragma unroll
            for (int nf = 0; nf < 4; ++nf) {
                const int d = nf * 16 + l15;
                float v = dgen ? vmean[b * 1024 + h * 64 + d] : osc[nf][r] * inv;
                AO[((size_t)(b * 1024 + qo)) * 1024 + h * 64 + d] = f2bf(v);
            }
        }
        __syncthreads();  // protect LDS across phases
    }
}

// ---------------------------------------------------------------------------
extern "C" void kernel_launch(void* const* d_in, const int* in_sizes, int n_in,
                              void* d_out, int out_size, void* d_ws, size_t ws_size,
                              hipStream_t stream) {
    const float* x       = (const float*)d_in[0];
    const unsigned* mraw = (const unsigned*)d_in[1];
    const float* pos     = (const float*)d_in[2];
    const unsigned* dec  = (const unsigned*)d_in[3];
    const float* Wq = (const float*)d_in[4];  const float* bq = (const float*)d_in[5];
    const float* Wk = (const float*)d_in[6];  const float* bk = (const float*)d_in[7];
    const float* Wv = (const float*)d_in[8];  const float* bv = (const float*)d_in[9];
    const float* Wo = (const float*)d_in[10]; const float* bo = (const float*)d_in[11];
    float* out = (float*)d_out;

    char* ws = (char*)d_ws;
    unsigned short* xb  = (unsigned short*)(ws);                 // 8 MB (reused later)
    unsigned short* wtq = (unsigned short*)(ws + (8u  << 20));
    unsigned short* wtk = (unsigned short*)(ws + (10u << 20));
    unsigned short* wtv = (unsigned short*)(ws + (12u << 20));
    unsigned short* wto = (unsigned short*)(ws + (14u << 20));
    unsigned short* Qb  = (unsigned short*)(ws + (16u << 20));
    unsigned short* Kb  = (unsigned short*)(ws + (24u << 20));
    unsigned short* Vb  = (unsigned short*)(ws + (32u << 20));
    unsigned short* AO  = (unsigned short*)(ws + (40u << 20));
    int* mcanon         = (int*)(ws + (48u << 20));
    // vsum scratch overlaps xb region — only used AFTER the Q/K/V GEMMs.
    float* part  = (float*)(ws);                 // 256 KB
    float* vmean = (float*)(ws + (1u << 19));    // 16 KB @ +512KB

    prep_mask_kernel<<<1, 1024, 0, stream>>>(mraw, mcanon);
    conv_x_kernel<<<4096, 256, 0, stream>>>(x, xb);
    dim3 tg(16, 16);
    conv_wt_kernel<<<tg, 256, 0, stream>>>(Wq, wtq);
    conv_wt_kernel<<<tg, 256, 0, stream>>>(Wk, wtk);
    conv_wt_kernel<<<tg, 256, 0, stream>>>(Wv, wtv);
    conv_wt_kernel<<<tg, 256, 0, stream>>>(Wo, wto);

    dim3 gg(8, 32);  // N/128, M/128
    gemm_bf16<1><<<gg, 256, 0, stream>>>(xb, wtq, bq, Qb, 4096, 1024, 1024);
    gemm_bf16<1><<<gg, 256, 0, stream>>>(xb, wtk, bk, Kb, 4096, 1024, 1024);
    gemm_bf16<1><<<gg, 256, 0, stream>>>(xb, wtv, bv, Vb, 4096, 1024, 1024);

    vsum_part<<<dim3(16, 4), 256, 0, stream>>>(Vb, part);
    vsum_reduce<<<4, 256, 0, stream>>>(part, vmean);

    attn_kernel<<<dim3(8, 16, 4), 256, 0, stream>>>(Qb, Kb, Vb, pos, mcanon, dec, vmean, AO);

    gemm_bf16<0><<<gg, 256, 0, stream>>>(AO, wto, bo, out, 4096, 1024, 1024);
}